// Round 2
// baseline (183.512 us; speedup 1.0000x reference)
//
#include <hip/hip_runtime.h>
#include <math.h>

#define DD 4096
#define EE 64
#define BK 64
#define NEG_SENTINEL -1.0e30f

// global -> LDS direct copy, 16B per lane. LDS dest must be wave-uniform base;
// per-lane global src carries the swizzle (m173 pattern).
__device__ __forceinline__ void gload16(const void* g, void* l) {
  __builtin_amdgcn_global_load_lds(
      (const __attribute__((address_space(1))) uint32_t*)(uintptr_t)g,
      (__attribute__((address_space(3))) uint32_t*)(uint32_t)(uintptr_t)l, 16,
      0, 0);
}

// ---------------------------------------------------------------------------
// Kernel 1: partial GEMM  logits[n][e] = sum_k hidden[n][k] * gate_w[e][k]
// Tile: 64 rows x 64 experts x BK=64 k. 256 threads (4 waves), thread 4x4.
// LDS physical layout (A and B identical):
//   byte(r, c) = r*256 + ((c ^ ((r>>2)&7)) << 4)   (c = k-float4-chunk 0..15)
// achieved by global_load_lds with pre-swizzled per-lane source columns.
// Read: addr = tx*1024 + i*256 + ((kk ^ (tx&7))<<4) -> bank-conflict-free.
// 2-phase pipeline: STAGE(next buf) -> compute(cur) -> __syncthreads().
// ---------------------------------------------------------------------------
template <int KSPLIT>
__global__ __launch_bounds__(256, 2) void gemm_partial(
    const float* __restrict__ hidden, const float* __restrict__ gate_w,
    float* __restrict__ part, int nrows) {
  __shared__ __align__(16) char smem[65536];  // 2 bufs x (A 16KB + B 16KB)

  const int tid = threadIdx.x;
  const int lane = tid & 63;
  const int wv = tid >> 6;  // wave 0..3
  const int tx = tid & 15;
  const int ty = tid >> 4;  // 0..15
  const int m0 = blockIdx.x * 64;
  const int kslice = DD / KSPLIT;
  const int nt = kslice / BK;
  const int k0 = blockIdx.y * kslice;

  // Staging: wave wv owns segments g = 4*wv + i (i=0..3) of each tile.
  // Segment g = 64 float4 slots = rows 4g..4g+3, columns permuted:
  //   lane l -> row 4g + (l>>4), chunk (l&15) ^ (g&7)
  const char* pA[4];
  const char* pB[4];
#pragma unroll
  for (int i = 0; i < 4; i++) {
    const int g = 4 * wv + i;
    const int row = 4 * g + (lane >> 4);
    const int col = ((lane & 15) ^ (g & 7)) << 4;  // bytes in 256B window
    pA[i] = (const char*)hidden + ((size_t)(m0 + row) * DD + k0) * 4 + col;
    pB[i] = (const char*)gate_w + ((size_t)row * DD + k0) * 4 + col;
  }

  auto stage = [&](int bufsel) {
    char* bA = smem + bufsel * 32768 + wv * 4096;
    char* bB = bA + 16384;
#pragma unroll
    for (int i = 0; i < 4; i++) {
      gload16(pA[i], bA + i * 1024);
      gload16(pB[i], bB + i * 1024);
      pA[i] += BK * 4;
      pB[i] += BK * 4;
    }
  };

  float acc[4][4] = {};
  const int sA = tx & 7;
  const int sB = ty & 7;

  int buf = 0;
  stage(0);
  __syncthreads();  // drains vmcnt(0): buf0 ready

  for (int t = 0; t < nt; t++) {
    if (t + 1 < nt) stage(buf ^ 1);  // issue next tile's loads first
    const char* base = smem + buf * 32768;
    const char* aBase = base + (tx << 10);
    const char* bBase = base + 16384 + (ty << 10);
#pragma unroll
    for (int kk = 0; kk < 16; kk++) {
      const int oa = (kk ^ sA) << 4;
      const int ob = (kk ^ sB) << 4;
      float4 av[4], bv[4];
#pragma unroll
      for (int i = 0; i < 4; i++)
        av[i] = *(const float4*)(aBase + oa + i * 256);
#pragma unroll
      for (int j = 0; j < 4; j++)
        bv[j] = *(const float4*)(bBase + ob + j * 256);
#pragma unroll
      for (int i = 0; i < 4; i++)
#pragma unroll
        for (int j = 0; j < 4; j++) {
          acc[i][j] = fmaf(av[i].x, bv[j].x, acc[i][j]);
          acc[i][j] = fmaf(av[i].y, bv[j].y, acc[i][j]);
          acc[i][j] = fmaf(av[i].z, bv[j].z, acc[i][j]);
          acc[i][j] = fmaf(av[i].w, bv[j].w, acc[i][j]);
        }
    }
    __syncthreads();  // drains this iter's stage + all LDS reads
    buf ^= 1;
  }

  // Write partial logits: part[ks][row][e]
  float* dst = part + (size_t)blockIdx.y * nrows * EE;
#pragma unroll
  for (int i = 0; i < 4; i++) {
    float4 v = make_float4(acc[i][0], acc[i][1], acc[i][2], acc[i][3]);
    *(float4*)&dst[(size_t)(m0 + 4 * tx + i) * EE + 4 * ty] = v;
  }
}

// ---------------------------------------------------------------------------
// Kernel 2: reduce K-split partials, sqrt(softplus), top-8 (lower-index
// tie-break like lax.top_k), renormalize, scatter probs + routing map.
// One wave (64 lanes) per row; lane == expert.
// ---------------------------------------------------------------------------
__global__ __launch_bounds__(256) void topk_kernel(
    const float* __restrict__ part, const float* __restrict__ bias,
    float* __restrict__ out, int nrows, int ksplit) {
  const int lane = threadIdx.x & 63;
  const int row = blockIdx.x * 4 + (threadIdx.x >> 6);

  float logit = 0.0f;
  for (int s = 0; s < ksplit; s++)
    logit += part[(size_t)s * nrows * EE + (size_t)row * EE + lane];

  // softplus, numerically stable
  float sp = (logit > 0.0f) ? (logit + log1pf(expf(-logit)))
                            : log1pf(expf(logit));
  float score = sqrtf(sp);
  float sel = score + bias[lane];

  float denom = 0.0f;
  bool chosen = false;
#pragma unroll
  for (int t = 0; t < 8; t++) {
    float v = sel;
    int idx = lane;
#pragma unroll
    for (int m = 1; m < 64; m <<= 1) {
      float ov = __shfl_xor(v, m, 64);
      int oi = __shfl_xor(idx, m, 64);
      if (ov > v || (ov == v && oi < idx)) {
        v = ov;
        idx = oi;
      }
    }
    float wscore = __shfl(score, idx, 64);
    denom += wscore;
    if (lane == idx) {
      chosen = true;
      sel = NEG_SENTINEL;
    }
  }
  denom = fmaxf(denom, 1e-12f);

  out[(size_t)row * EE + lane] = chosen ? (score / denom) : 0.0f;
  out[(size_t)nrows * EE + (size_t)row * EE + lane] = chosen ? 1.0f : 0.0f;
}

// ---------------------------------------------------------------------------
extern "C" void kernel_launch(void* const* d_in, const int* in_sizes, int n_in,
                              void* d_out, int out_size, void* d_ws,
                              size_t ws_size, hipStream_t stream) {
  const float* hidden = (const float*)d_in[0];
  const float* gate_w = (const float*)d_in[1];
  const float* bias = (const float*)d_in[2];
  float* out = (float*)d_out;
  float* part = (float*)d_ws;

  const int nrows = in_sizes[0] / DD;  // 16384

  const size_t per = (size_t)nrows * EE * sizeof(float);  // 4 MiB
  int ksplit = (ws_size >= 4 * per) ? 4 : ((ws_size >= 2 * per) ? 2 : 1);

  dim3 block(256);
  dim3 grid(nrows / 64, ksplit);
  if (ksplit == 4)
    gemm_partial<4><<<grid, block, 0, stream>>>(hidden, gate_w, part, nrows);
  else if (ksplit == 2)
    gemm_partial<2><<<grid, block, 0, stream>>>(hidden, gate_w, part, nrows);
  else
    gemm_partial<1><<<grid, block, 0, stream>>>(hidden, gate_w, part, nrows);

  topk_kernel<<<dim3(nrows / 4), dim3(256), 0, stream>>>(part, bias, out,
                                                         nrows, ksplit);
}